// Round 5
// baseline (594.492 us; speedup 1.0000x reference)
//
#include <hip/hip_runtime.h>
#include <hip/hip_cooperative_groups.h>
#include <cstdint>
#include <cstddef>

namespace cg = cooperative_groups;

#define DEV __device__ __forceinline__

typedef __bf16 bf16x8 __attribute__((ext_vector_type(8)));
typedef float f32x4 __attribute__((ext_vector_type(4)));

DEV ushort f2b(float f) {
  uint u = __float_as_uint(f);
  return (ushort)((u + 0x7FFFu + ((u >> 16) & 1u)) >> 16);
}

DEV ushort4 cvt4(float4 v) {
  ushort4 o; o.x = f2b(v.x); o.y = f2b(v.y); o.z = f2b(v.z); o.w = f2b(v.w);
  return o;
}

DEV float4 shfl_xor4(float4 v, int m) {
  float4 r;
  r.x = __shfl_xor(v.x, m); r.y = __shfl_xor(v.y, m);
  r.z = __shfl_xor(v.z, m); r.w = __shfl_xor(v.w, m);
  return r;
}

DEV void unpack8(uint4 u, float4& lo, float4& hi) {
  lo.x = __uint_as_float(u.x << 16);
  lo.y = __uint_as_float(u.x & 0xFFFF0000u);
  lo.z = __uint_as_float(u.y << 16);
  lo.w = __uint_as_float(u.y & 0xFFFF0000u);
  hi.x = __uint_as_float(u.z << 16);
  hi.y = __uint_as_float(u.z & 0xFFFF0000u);
  hi.z = __uint_as_float(u.w << 16);
  hi.w = __uint_as_float(u.w & 0xFFFF0000u);
}

DEV void fma8(float4& alo, float4& ahi, float w, uint4 u) {
  float4 lo, hi; unpack8(u, lo, hi);
  alo.x = fmaf(w, lo.x, alo.x); alo.y = fmaf(w, lo.y, alo.y);
  alo.z = fmaf(w, lo.z, alo.z); alo.w = fmaf(w, lo.w, alo.w);
  ahi.x = fmaf(w, hi.x, ahi.x); ahi.y = fmaf(w, hi.y, ahi.y);
  ahi.z = fmaf(w, hi.z, ahi.z); ahi.w = fmaf(w, hi.w, ahi.w);
}

// ================= cooperative prep: zero+cvt | count | scan | scatter =======
__global__ __launch_bounds__(256) void k_coop_prep(
    const float* x, ushort* xb,
    const float* W0, const float* W1, const float* W2, ushort* Wb,
    const int* ei, int2* edata, int* cnt, int* off, int* cursor,
    float* dinv, int* btot, int* bpre, int N, int E) {
  cg::grid_group grid = cg::this_grid();
  int gsz = (int)gridDim.x * 256;
  int gtid = (int)blockIdx.x * 256 + (int)threadIdx.x;
  int t = threadIdx.x, ln = t & 63, wv = t >> 6;
  __shared__ int ws[4];
  int NB = (N + 255) / 256;

  // ---- P0: zero cnt, convert W and x to bf16 ----
  for (int i = gtid; i < N; i += gsz) cnt[i] = 0;
  for (int i = gtid; i < 12288; i += gsz) {  // 3 * 16384 / 4 ushort4 units
    int mi = i >> 12;
    const float* src = (mi == 0) ? W0 : (mi == 1) ? W1 : W2;
    int j = (i & 4095) << 2;
    float4 v = *(const float4*)(src + j);
    *(ushort4*)(Wb + ((size_t)i << 2)) = cvt4(v);
  }
  int n4 = N * 32;  // N*128/4
  for (int i = gtid; i < n4; i += gsz)
    ((ushort4*)xb)[i] = cvt4(((const float4*)x)[i]);
  grid.sync();

  // ---- P1: degree count ----
  const int* col = ei + E;
  for (int e = gtid; e < E; e += gsz) atomicAdd(&cnt[col[e]], 1);
  grid.sync();

  // ---- P2a: per-256-chunk scan ----
  for (int c = blockIdx.x; c < NB; c += gridDim.x) {
    int i = c * 256 + t;
    int v = (i < N) ? cnt[i] : 0;
    int inc = v;
#pragma unroll
    for (int o = 1; o < 64; o <<= 1) {
      int u = __shfl_up(inc, o);
      if (ln >= o) inc += u;
    }
    if (ln == 63) ws[wv] = inc;
    __syncthreads();
    if (t == 0) {
      int s = 0;
#pragma unroll
      for (int w = 0; w < 4; ++w) { int tmp = ws[w]; ws[w] = s; s += tmp; }
    }
    __syncthreads();
    int excl = ws[wv] + inc - v;
    if (i < N) {
      off[i] = excl;
      dinv[i] = rsqrtf((float)v + 1.0f);
    }
    if (t == 255) btot[c] = excl + v;
    __syncthreads();
  }
  grid.sync();

  // ---- P2b: block 0 scans block totals (NB <= 256) ----
  if (blockIdx.x == 0) {
    int v = (t < NB) ? btot[t] : 0;
    int inc = v;
#pragma unroll
    for (int o = 1; o < 64; o <<= 1) {
      int u = __shfl_up(inc, o);
      if (ln >= o) inc += u;
    }
    if (ln == 63) ws[wv] = inc;
    __syncthreads();
    if (t == 0) {
      int s = 0;
#pragma unroll
      for (int w = 0; w < 4; ++w) { int tmp = ws[w]; ws[w] = s; s += tmp; }
    }
    __syncthreads();
    int excl = ws[wv] + inc - v;
    if (t < NB) bpre[t] = excl;
    if (t == 255) off[N] = excl + v;
  }
  grid.sync();

  // ---- P2c: add block prefix, init cursor ----
  for (int c = blockIdx.x; c < NB; c += gridDim.x) {
    int i = c * 256 + t;
    if (i < N) {
      int o = off[i] + bpre[c];
      off[i] = o;
      cursor[i] = o;
    }
  }
  grid.sync();

  // ---- P3: scatter edges into CSR ----
  for (int e = gtid; e < E; e += gsz) {
    int s = ei[e], d = col[e];
    float w = dinv[s] * dinv[d];
    int p = atomicAdd(&cursor[d], 1);
    int2 v; v.x = s; v.y = __float_as_int(w);
    edata[p] = v;
  }
}

// ================= MFMA GEMM: h_all[r][m*128+c] = bf16(x @ W_m^T + b_m) =====
__global__ __launch_bounds__(256, 2) void k_gemm_mfma(
    const ushort* __restrict__ xb, const ushort* __restrict__ Wb,
    const float* __restrict__ b_hp, const float* __restrict__ b_lp,
    const float* __restrict__ b_i,
    ushort* __restrict__ h_all, int N) {
  int m = blockIdx.y;
  const float* bias = (m == 0) ? b_hp : (m == 1) ? b_lp : b_i;
  int lane = (int)threadIdx.x & 63, wv = (int)threadIdx.x >> 6;
  int r = lane & 15, g = lane >> 4;

  const ushort* wp = Wb + m * 16384 + r * 128 + g * 8;
  bf16x8 Bf[8][4];
#pragma unroll
  for (int ct = 0; ct < 8; ++ct)
#pragma unroll
    for (int kc = 0; kc < 4; ++kc)
      Bf[ct][kc] = *(const bf16x8*)(const void*)(wp + ct * 2048 + kc * 32);

  float bv[8];
#pragma unroll
  for (int ct = 0; ct < 8; ++ct) bv[ct] = bias[ct * 16 + r];

  int NT = N >> 4;
  int stride = gridDim.x * 4;
  int t = blockIdx.x * 4 + wv;
  if (t >= NT) return;

  const ushort* ap0 = xb + r * 128 + g * 8;
  bf16x8 Af[4];
#pragma unroll
  for (int kc = 0; kc < 4; ++kc)
    Af[kc] = *(const bf16x8*)(const void*)(ap0 + (size_t)t * 2048 + kc * 32);

  while (t < NT) {
    int tn = t + stride;
    bf16x8 Afn[4];
    if (tn < NT) {
#pragma unroll
      for (int kc = 0; kc < 4; ++kc)
        Afn[kc] = *(const bf16x8*)(const void*)(ap0 + (size_t)tn * 2048 + kc * 32);
    }
    f32x4 acc[8];
#pragma unroll
    for (int ct = 0; ct < 8; ++ct) {
      f32x4 c; c[0] = bv[ct]; c[1] = bv[ct]; c[2] = bv[ct]; c[3] = bv[ct];
      acc[ct] = c;
    }
#pragma unroll
    for (int kc = 0; kc < 4; ++kc)
#pragma unroll
      for (int ct = 0; ct < 8; ++ct)
        acc[ct] = __builtin_amdgcn_mfma_f32_16x16x32_bf16(Af[kc], Bf[ct][kc], acc[ct], 0, 0, 0);

    ushort* op = h_all + (size_t)((t << 4) + g * 4) * 384 + m * 128 + r;
#pragma unroll
    for (int ct = 0; ct < 8; ++ct)
#pragma unroll
      for (int j = 0; j < 4; ++j) {
        float v = acc[ct][j];
        if (m == 2) v = fmaxf(v, 0.f);
        op[(size_t)j * 384 + ct * 16] = f2b(v);
      }
#pragma unroll
    for (int kc = 0; kc < 4; ++kc) Af[kc] = Afn[kc];
    t = tn;
  }
}

// ================= fused aggregation + epilogue (wave/node, 2 edges/load) ===
// h_all row: [0:128]=h_hp, [128:256]=h_lp, [256:384]=H_i (bf16).
// Half-wave (32 lanes x 16B) covers the 512B hp|lp row of one edge source.
__global__ __launch_bounds__(256) void k_agg_final(
    const ushort* __restrict__ h_all, const float* __restrict__ dinv,
    const int* __restrict__ off, const int2* __restrict__ edata,
    const float* __restrict__ wlh, const float* __restrict__ wll,
    const float* __restrict__ wli,
    const float* __restrict__ pbh, const float* __restrict__ pbl,
    const float* __restrict__ pbi,
    float* __restrict__ out, int N) {
  int wv = (int)threadIdx.x >> 6;
  int lane = (int)threadIdx.x & 63;
  int node = blockIdx.x * 4 + wv;
  if (node >= N) return;
  int sl = lane & 31;    // 16B segment within 512B row
  int half = lane >> 5;  // which edge of a pair

  const ushort* hb = h_all + sl * 8;
  int p0 = off[node], p1 = off[node + 1];

  float4 a0l = {0,0,0,0}, a0h = {0,0,0,0}, a1l = {0,0,0,0}, a1h = {0,0,0,0};
  float4 a2l = {0,0,0,0}, a2h = {0,0,0,0}, a3l = {0,0,0,0}, a3h = {0,0,0,0};

  int p = p0 + half;  // this half's edges: p0+half, +2, +4, ...
  for (; p < p1 - 6; p += 8) {  // 4 edges per half per iter -> 8/wave in flight
    int2 e0 = edata[p], e1 = edata[p + 2], e2 = edata[p + 4], e3 = edata[p + 6];
    uint4 u0 = *(const uint4*)(const void*)(hb + (size_t)e0.x * 384);
    uint4 u1 = *(const uint4*)(const void*)(hb + (size_t)e1.x * 384);
    uint4 u2 = *(const uint4*)(const void*)(hb + (size_t)e2.x * 384);
    uint4 u3 = *(const uint4*)(const void*)(hb + (size_t)e3.x * 384);
    fma8(a0l, a0h, __int_as_float(e0.y), u0);
    fma8(a1l, a1h, __int_as_float(e1.y), u1);
    fma8(a2l, a2h, __int_as_float(e2.y), u2);
    fma8(a3l, a3h, __int_as_float(e3.y), u3);
  }
  for (; p < p1; p += 2) {
    int2 e0 = edata[p];
    uint4 u0 = *(const uint4*)(const void*)(hb + (size_t)e0.x * 384);
    fma8(a0l, a0h, __int_as_float(e0.y), u0);
  }

  float4 s_lo, s_hi;
  s_lo.x = (a0l.x + a1l.x) + (a2l.x + a3l.x);
  s_lo.y = (a0l.y + a1l.y) + (a2l.y + a3l.y);
  s_lo.z = (a0l.z + a1l.z) + (a2l.z + a3l.z);
  s_lo.w = (a0l.w + a1l.w) + (a2l.w + a3l.w);
  s_hi.x = (a0h.x + a1h.x) + (a2h.x + a3h.x);
  s_hi.y = (a0h.y + a1h.y) + (a2h.y + a3h.y);
  s_hi.z = (a0h.z + a1h.z) + (a2h.z + a3h.z);
  s_hi.w = (a0h.w + a1h.w) + (a2h.w + a3h.w);

  // combine the two halves (each processed disjoint edges)
  float4 xlo = shfl_xor4(s_lo, 32), xhi = shfl_xor4(s_hi, 32);
  s_lo.x += xlo.x; s_lo.y += xlo.y; s_lo.z += xlo.z; s_lo.w += xlo.w;
  s_hi.x += xhi.x; s_hi.y += xhi.y; s_hi.z += xhi.z; s_hi.w += xhi.w;

  // self-loop term
  float di = dinv[node], wself = di * di;
  uint4 su = *(const uint4*)(const void*)(h_all + (size_t)node * 384 + sl * 8);
  float4 self_lo, self_hi; unpack8(su, self_lo, self_hi);
  s_lo.x = fmaf(wself, self_lo.x, s_lo.x); s_lo.y = fmaf(wself, self_lo.y, s_lo.y);
  s_lo.z = fmaf(wself, self_lo.z, s_lo.z); s_lo.w = fmaf(wself, self_lo.w, s_lo.w);
  s_hi.x = fmaf(wself, self_hi.x, s_hi.x); s_hi.y = fmaf(wself, self_hi.y, s_hi.y);
  s_hi.z = fmaf(wself, self_hi.z, s_hi.z); s_hi.w = fmaf(wself, self_hi.w, s_hi.w);

  // lanes sl<16 hold hp cols (Hh = relu(self - agg)); sl>=16 hold lp (Hl = relu(agg))
  bool lpside = (sl >= 16);
  float4 t_lo, t_hi;
  t_lo.x = lpside ? fmaxf(s_lo.x, 0.f) : fmaxf(self_lo.x - s_lo.x, 0.f);
  t_lo.y = lpside ? fmaxf(s_lo.y, 0.f) : fmaxf(self_lo.y - s_lo.y, 0.f);
  t_lo.z = lpside ? fmaxf(s_lo.z, 0.f) : fmaxf(self_lo.z - s_lo.z, 0.f);
  t_lo.w = lpside ? fmaxf(s_lo.w, 0.f) : fmaxf(self_lo.w - s_lo.w, 0.f);
  t_hi.x = lpside ? fmaxf(s_hi.x, 0.f) : fmaxf(self_hi.x - s_hi.x, 0.f);
  t_hi.y = lpside ? fmaxf(s_hi.y, 0.f) : fmaxf(self_hi.y - s_hi.y, 0.f);
  t_hi.z = lpside ? fmaxf(s_hi.z, 0.f) : fmaxf(self_hi.z - s_hi.z, 0.f);
  t_hi.w = lpside ? fmaxf(s_hi.w, 0.f) : fmaxf(self_hi.w - s_hi.w, 0.f);

  // opposite side's values (for lanes <16: the Hl of same cols)
  float4 o_lo = shfl_xor4(t_lo, 16), o_hi = shfl_xor4(t_hi, 16);

  // identity branch
  int c0 = (sl & 15) * 8;
  uint4 hu = *(const uint4*)(const void*)(h_all + (size_t)node * 384 + 256 + c0);
  float4 hi_lo, hi_hi; unpack8(hu, hi_lo, hi_hi);

  const float* wsel = lpside ? wll : wlh;
  float4 w_lo = *(const float4*)(wsel + c0);
  float4 w_hi = *(const float4*)(wsel + c0 + 4);
  float4 wi_lo = *(const float4*)(wli + c0);
  float4 wi_hi = *(const float4*)(wli + c0 + 4);

  float dpart = t_lo.x * w_lo.x + t_lo.y * w_lo.y + t_lo.z * w_lo.z + t_lo.w * w_lo.w
              + t_hi.x * w_hi.x + t_hi.y * w_hi.y + t_hi.z * w_hi.z + t_hi.w * w_hi.w;
  float dipart = hi_lo.x * wi_lo.x + hi_lo.y * wi_lo.y + hi_lo.z * wi_lo.z + hi_lo.w * wi_lo.w
               + hi_hi.x * wi_hi.x + hi_hi.y * wi_hi.y + hi_hi.z * wi_hi.z + hi_hi.w * wi_hi.w;
#pragma unroll
  for (int o = 1; o <= 8; o <<= 1) {
    dpart += __shfl_xor(dpart, o);
    dipart += __shfl_xor(dipart, o);
  }
  float dother = __shfl_xor(dpart, 16);
  float dh = lpside ? dother : dpart;
  float dl = lpside ? dpart : dother;

  float a_h = 1.f / (1.f + __expf(-(dh + pbh[0])));
  float a_l = 1.f / (1.f + __expf(-(dl + pbl[0])));
  float a_i = 1.f / (1.f + __expf(-(dipart + pbi[0])));

  if (lane < 16) {  // these lanes: t=Hh, o=Hl for cols c0..c0+7
    f32x4 r_lo, r_hi;
    r_lo[0] = a_h * t_lo.x + a_l * o_lo.x + a_i * hi_lo.x;
    r_lo[1] = a_h * t_lo.y + a_l * o_lo.y + a_i * hi_lo.y;
    r_lo[2] = a_h * t_lo.z + a_l * o_lo.z + a_i * hi_lo.z;
    r_lo[3] = a_h * t_lo.w + a_l * o_lo.w + a_i * hi_lo.w;
    r_hi[0] = a_h * t_hi.x + a_l * o_hi.x + a_i * hi_hi.x;
    r_hi[1] = a_h * t_hi.y + a_l * o_hi.y + a_i * hi_hi.y;
    r_hi[2] = a_h * t_hi.z + a_l * o_hi.z + a_i * hi_hi.z;
    r_hi[3] = a_h * t_hi.w + a_l * o_hi.w + a_i * hi_hi.w;
    f32x4* po = (f32x4*)(out + (size_t)node * 128 + c0);
    __builtin_nontemporal_store(r_lo, po);
    __builtin_nontemporal_store(r_hi, po + 1);
  }
}

// ================= launch ===================================================
extern "C" void kernel_launch(void* const* d_in, const int* in_sizes, int n_in,
                              void* d_out, int out_size, void* d_ws, size_t ws_size,
                              hipStream_t stream) {
  const float* x     = (const float*)d_in[0];
  const int*   ei    = (const int*)d_in[1];
  const float* W_hp  = (const float*)d_in[2];
  const float* b_hp  = (const float*)d_in[3];
  const float* W_lp  = (const float*)d_in[4];
  const float* b_lp  = (const float*)d_in[5];
  const float* W_i   = (const float*)d_in[6];
  const float* b_i   = (const float*)d_in[7];
  const float* wlh   = (const float*)d_in[8];
  const float* pbh   = (const float*)d_in[9];
  const float* wll   = (const float*)d_in[10];
  const float* pbl   = (const float*)d_in[11];
  const float* wli   = (const float*)d_in[12];
  const float* pbi   = (const float*)d_in[13];
  float* out = (float*)d_out;

  int N = in_sizes[0] / 128;
  int E = in_sizes[1] / 2;

  ushort* xb    = (ushort*)d_ws;                  // N*128
  ushort* h_all = xb + (size_t)N * 128;           // N*384
  ushort* Wb    = h_all + (size_t)N * 384;        // 3*16384
  int2*   edata = (int2*)(Wb + 3 * 16384);        // E
  float*  dinv  = (float*)(edata + E);            // N
  int*    cnt   = (int*)(dinv + N);               // N
  int*    off   = cnt + N;                        // N+1
  int*    cursor= off + N + 1;                    // N
  int*    btot  = cursor + N;                     // 256
  int*    bpre  = btot + 256;                     // 256

  void* args[] = {(void*)&x, (void*)&xb, (void*)&W_hp, (void*)&W_lp, (void*)&W_i,
                  (void*)&Wb, (void*)&ei, (void*)&edata, (void*)&cnt, (void*)&off,
                  (void*)&cursor, (void*)&dinv, (void*)&btot, (void*)&bpre,
                  (void*)&N, (void*)&E};
  (void)hipLaunchCooperativeKernel((const void*)k_coop_prep, dim3(512), dim3(256),
                                   args, 0, stream);
  k_gemm_mfma<<<dim3(391, 3), 256, 0, stream>>>(xb, Wb, b_hp, b_lp, b_i, h_all, N);
  k_agg_final<<<(N + 3) / 4, 256, 0, stream>>>(
      h_all, dinv, off, edata, wlh, wll, wli, pbh, pbl, pbi, out, N);
}

// Round 6
// 278.439 us; speedup vs baseline: 2.1351x; 2.1351x over previous
//
#include <hip/hip_runtime.h>
#include <cstdint>
#include <cstddef>

#define DEV __device__ __forceinline__

typedef __bf16 bf16x8 __attribute__((ext_vector_type(8)));
typedef float f32x4 __attribute__((ext_vector_type(4)));

DEV ushort f2b(float f) {
  uint u = __float_as_uint(f);
  return (ushort)((u + 0x7FFFu + ((u >> 16) & 1u)) >> 16);
}

DEV ushort4 cvt4(float4 v) {
  ushort4 o; o.x = f2b(v.x); o.y = f2b(v.y); o.z = f2b(v.z); o.w = f2b(v.w);
  return o;
}

DEV float4 shfl_xor4(float4 v, int m) {
  float4 r;
  r.x = __shfl_xor(v.x, m); r.y = __shfl_xor(v.y, m);
  r.z = __shfl_xor(v.z, m); r.w = __shfl_xor(v.w, m);
  return r;
}

DEV void unpack8(uint4 u, float4& lo, float4& hi) {
  lo.x = __uint_as_float(u.x << 16);
  lo.y = __uint_as_float(u.x & 0xFFFF0000u);
  lo.z = __uint_as_float(u.y << 16);
  lo.w = __uint_as_float(u.y & 0xFFFF0000u);
  hi.x = __uint_as_float(u.z << 16);
  hi.y = __uint_as_float(u.z & 0xFFFF0000u);
  hi.z = __uint_as_float(u.w << 16);
  hi.w = __uint_as_float(u.w & 0xFFFF0000u);
}

DEV void fma8(float4& alo, float4& ahi, float w, uint4 u) {
  float4 lo, hi; unpack8(u, lo, hi);
  alo.x = fmaf(w, lo.x, alo.x); alo.y = fmaf(w, lo.y, alo.y);
  alo.z = fmaf(w, lo.z, alo.z); alo.w = fmaf(w, lo.w, alo.w);
  ahi.x = fmaf(w, hi.x, ahi.x); ahi.y = fmaf(w, hi.y, ahi.y);
  ahi.z = fmaf(w, hi.z, ahi.z); ahi.w = fmaf(w, hi.w, ahi.w);
}

// ============ prep: zero cnt + convert W,x to bf16 (one kernel) =============
__global__ __launch_bounds__(256) void k_prep(
    const float* __restrict__ x, ushort* __restrict__ xb,
    const float* __restrict__ W0, const float* __restrict__ W1,
    const float* __restrict__ W2, ushort* __restrict__ Wb,
    int* __restrict__ cnt, int N) {
  int gsz = (int)gridDim.x * 256;
  int gtid = (int)blockIdx.x * 256 + (int)threadIdx.x;
  for (int i = gtid; i < N; i += gsz) cnt[i] = 0;
  for (int i = gtid; i < 12288; i += gsz) {  // 3*16384/4 ushort4 units
    int mi = i >> 12;
    const float* src = (mi == 0) ? W0 : (mi == 1) ? W1 : W2;
    int j = (i & 4095) << 2;
    *(ushort4*)(Wb + ((size_t)i << 2)) = cvt4(*(const float4*)(src + j));
  }
  int n4 = N * 32;
  for (int i = gtid; i < n4; i += gsz)
    ((ushort4*)xb)[i] = cvt4(((const float4*)x)[i]);
}

// ---------------- degree count ----------------
__global__ __launch_bounds__(256) void k_count(const int* __restrict__ col,
                                               int* __restrict__ cnt, int E) {
  int e = blockIdx.x * 256 + threadIdx.x;
  if (e < E) atomicAdd(&cnt[col[e]], 1);
}

// ---------------- scan phase A: per-256-chunk scan + dinv ----------------
__global__ __launch_bounds__(256) void k_scanA(const int* __restrict__ cnt,
                                               int* __restrict__ off,
                                               float* __restrict__ dinv,
                                               int* __restrict__ btot, int N) {
  __shared__ int ws[4];
  int t = threadIdx.x, ln = t & 63, wv = t >> 6;
  int i = blockIdx.x * 256 + t;
  int v = (i < N) ? cnt[i] : 0;
  int inc = v;
#pragma unroll
  for (int o = 1; o < 64; o <<= 1) {
    int u = __shfl_up(inc, o);
    if (ln >= o) inc += u;
  }
  if (ln == 63) ws[wv] = inc;
  __syncthreads();
  if (t == 0) {
    int s = 0;
#pragma unroll
    for (int w = 0; w < 4; ++w) { int tmp = ws[w]; ws[w] = s; s += tmp; }
  }
  __syncthreads();
  int excl = ws[wv] + inc - v;
  if (i < N) {
    off[i] = excl;
    dinv[i] = rsqrtf((float)v + 1.0f);
  }
  if (t == 255) btot[blockIdx.x] = excl + v;
}

// -------- scan phase B+C fused: every block rescans btot, applies prefix ----
__global__ __launch_bounds__(256) void k_scanBC(int* __restrict__ off,
                                                const int* __restrict__ btot,
                                                int* __restrict__ cursor,
                                                int N, int E, int NB) {
  __shared__ int ws[4];
  __shared__ int pre_sh[256];
  int t = threadIdx.x, ln = t & 63, wv = t >> 6;
  int v = (t < NB) ? btot[t] : 0;
  int inc = v;
#pragma unroll
  for (int o = 1; o < 64; o <<= 1) {
    int u = __shfl_up(inc, o);
    if (ln >= o) inc += u;
  }
  if (ln == 63) ws[wv] = inc;
  __syncthreads();
  if (t == 0) {
    int s = 0;
#pragma unroll
    for (int w = 0; w < 4; ++w) { int tmp = ws[w]; ws[w] = s; s += tmp; }
  }
  __syncthreads();
  pre_sh[t] = ws[wv] + inc - v;
  __syncthreads();
  int bpre = pre_sh[blockIdx.x];
  int i = blockIdx.x * 256 + t;
  if (i < N) {
    int o = off[i] + bpre;
    off[i] = o;
    cursor[i] = o;
  }
  if (blockIdx.x == 0 && t == 0) off[N] = E;
}

// ---------------- scatter edges into CSR ----------------
__global__ __launch_bounds__(256) void k_scatter(const int* __restrict__ ei,
                                                 const float* __restrict__ dinv,
                                                 int* __restrict__ cursor,
                                                 int2* __restrict__ edata, int E) {
  int e = blockIdx.x * 256 + threadIdx.x;
  if (e >= E) return;
  int s = ei[e], d = ei[E + e];
  float w = dinv[s] * dinv[d];
  int p = atomicAdd(&cursor[d], 1);
  int2 v; v.x = s; v.y = __float_as_int(w);
  edata[p] = v;
}

// ================= MFMA GEMM: h_all[r][m*128+c] = bf16(x @ W_m^T + b_m) =====
__global__ __launch_bounds__(256, 2) void k_gemm_mfma(
    const ushort* __restrict__ xb, const ushort* __restrict__ Wb,
    const float* __restrict__ b_hp, const float* __restrict__ b_lp,
    const float* __restrict__ b_i,
    ushort* __restrict__ h_all, int N) {
  int m = blockIdx.y;
  const float* bias = (m == 0) ? b_hp : (m == 1) ? b_lp : b_i;
  int lane = (int)threadIdx.x & 63, wv = (int)threadIdx.x >> 6;
  int r = lane & 15, g = lane >> 4;

  const ushort* wp = Wb + m * 16384 + r * 128 + g * 8;
  bf16x8 Bf[8][4];
#pragma unroll
  for (int ct = 0; ct < 8; ++ct)
#pragma unroll
    for (int kc = 0; kc < 4; ++kc)
      Bf[ct][kc] = *(const bf16x8*)(const void*)(wp + ct * 2048 + kc * 32);

  float bv[8];
#pragma unroll
  for (int ct = 0; ct < 8; ++ct) bv[ct] = bias[ct * 16 + r];

  int NT = N >> 4;
  int stride = gridDim.x * 4;
  int t = blockIdx.x * 4 + wv;
  if (t >= NT) return;

  const ushort* ap0 = xb + r * 128 + g * 8;
  bf16x8 Af[4];
#pragma unroll
  for (int kc = 0; kc < 4; ++kc)
    Af[kc] = *(const bf16x8*)(const void*)(ap0 + (size_t)t * 2048 + kc * 32);

  while (t < NT) {
    int tn = t + stride;
    bf16x8 Afn[4];
    if (tn < NT) {
#pragma unroll
      for (int kc = 0; kc < 4; ++kc)
        Afn[kc] = *(const bf16x8*)(const void*)(ap0 + (size_t)tn * 2048 + kc * 32);
    }
    f32x4 acc[8];
#pragma unroll
    for (int ct = 0; ct < 8; ++ct) {
      f32x4 c; c[0] = bv[ct]; c[1] = bv[ct]; c[2] = bv[ct]; c[3] = bv[ct];
      acc[ct] = c;
    }
#pragma unroll
    for (int kc = 0; kc < 4; ++kc)
#pragma unroll
      for (int ct = 0; ct < 8; ++ct)
        acc[ct] = __builtin_amdgcn_mfma_f32_16x16x32_bf16(Af[kc], Bf[ct][kc], acc[ct], 0, 0, 0);

    ushort* op = h_all + (size_t)((t << 4) + g * 4) * 384 + m * 128 + r;
#pragma unroll
    for (int ct = 0; ct < 8; ++ct)
#pragma unroll
      for (int j = 0; j < 4; ++j) {
        float v = acc[ct][j];
        if (m == 2) v = fmaxf(v, 0.f);
        op[(size_t)j * 384 + ct * 16] = f2b(v);
      }
#pragma unroll
    for (int kc = 0; kc < 4; ++kc) Af[kc] = Afn[kc];
    t = tn;
  }
}

// ================= fused aggregation + epilogue (wave/node, 2 edges/load) ===
__global__ __launch_bounds__(256) void k_agg_final(
    const ushort* __restrict__ h_all, const float* __restrict__ dinv,
    const int* __restrict__ off, const int2* __restrict__ edata,
    const float* __restrict__ wlh, const float* __restrict__ wll,
    const float* __restrict__ wli,
    const float* __restrict__ pbh, const float* __restrict__ pbl,
    const float* __restrict__ pbi,
    float* __restrict__ out, int N) {
  int wv = (int)threadIdx.x >> 6;
  int lane = (int)threadIdx.x & 63;
  int node = blockIdx.x * 4 + wv;
  if (node >= N) return;
  int sl = lane & 31;    // 16B segment within 512B row
  int half = lane >> 5;  // which edge of a pair

  const ushort* hb = h_all + sl * 8;
  int p0 = off[node], p1 = off[node + 1];

  float4 a0l = {0,0,0,0}, a0h = {0,0,0,0}, a1l = {0,0,0,0}, a1h = {0,0,0,0};
  float4 a2l = {0,0,0,0}, a2h = {0,0,0,0}, a3l = {0,0,0,0}, a3h = {0,0,0,0};

  int p = p0 + half;
  for (; p < p1 - 6; p += 8) {
    int2 e0 = edata[p], e1 = edata[p + 2], e2 = edata[p + 4], e3 = edata[p + 6];
    uint4 u0 = *(const uint4*)(const void*)(hb + (size_t)e0.x * 384);
    uint4 u1 = *(const uint4*)(const void*)(hb + (size_t)e1.x * 384);
    uint4 u2 = *(const uint4*)(const void*)(hb + (size_t)e2.x * 384);
    uint4 u3 = *(const uint4*)(const void*)(hb + (size_t)e3.x * 384);
    fma8(a0l, a0h, __int_as_float(e0.y), u0);
    fma8(a1l, a1h, __int_as_float(e1.y), u1);
    fma8(a2l, a2h, __int_as_float(e2.y), u2);
    fma8(a3l, a3h, __int_as_float(e3.y), u3);
  }
  for (; p < p1; p += 2) {
    int2 e0 = edata[p];
    uint4 u0 = *(const uint4*)(const void*)(hb + (size_t)e0.x * 384);
    fma8(a0l, a0h, __int_as_float(e0.y), u0);
  }

  float4 s_lo, s_hi;
  s_lo.x = (a0l.x + a1l.x) + (a2l.x + a3l.x);
  s_lo.y = (a0l.y + a1l.y) + (a2l.y + a3l.y);
  s_lo.z = (a0l.z + a1l.z) + (a2l.z + a3l.z);
  s_lo.w = (a0l.w + a1l.w) + (a2l.w + a3l.w);
  s_hi.x = (a0h.x + a1h.x) + (a2h.x + a3h.x);
  s_hi.y = (a0h.y + a1h.y) + (a2h.y + a3h.y);
  s_hi.z = (a0h.z + a1h.z) + (a2h.z + a3h.z);
  s_hi.w = (a0h.w + a1h.w) + (a2h.w + a3h.w);

  float4 xlo = shfl_xor4(s_lo, 32), xhi = shfl_xor4(s_hi, 32);
  s_lo.x += xlo.x; s_lo.y += xlo.y; s_lo.z += xlo.z; s_lo.w += xlo.w;
  s_hi.x += xhi.x; s_hi.y += xhi.y; s_hi.z += xhi.z; s_hi.w += xhi.w;

  float di = dinv[node], wself = di * di;
  uint4 su = *(const uint4*)(const void*)(h_all + (size_t)node * 384 + sl * 8);
  float4 self_lo, self_hi; unpack8(su, self_lo, self_hi);
  s_lo.x = fmaf(wself, self_lo.x, s_lo.x); s_lo.y = fmaf(wself, self_lo.y, s_lo.y);
  s_lo.z = fmaf(wself, self_lo.z, s_lo.z); s_lo.w = fmaf(wself, self_lo.w, s_lo.w);
  s_hi.x = fmaf(wself, self_hi.x, s_hi.x); s_hi.y = fmaf(wself, self_hi.y, s_hi.y);
  s_hi.z = fmaf(wself, self_hi.z, s_hi.z); s_hi.w = fmaf(wself, self_hi.w, s_hi.w);

  bool lpside = (sl >= 16);
  float4 t_lo, t_hi;
  t_lo.x = lpside ? fmaxf(s_lo.x, 0.f) : fmaxf(self_lo.x - s_lo.x, 0.f);
  t_lo.y = lpside ? fmaxf(s_lo.y, 0.f) : fmaxf(self_lo.y - s_lo.y, 0.f);
  t_lo.z = lpside ? fmaxf(s_lo.z, 0.f) : fmaxf(self_lo.z - s_lo.z, 0.f);
  t_lo.w = lpside ? fmaxf(s_lo.w, 0.f) : fmaxf(self_lo.w - s_lo.w, 0.f);
  t_hi.x = lpside ? fmaxf(s_hi.x, 0.f) : fmaxf(self_hi.x - s_hi.x, 0.f);
  t_hi.y = lpside ? fmaxf(s_hi.y, 0.f) : fmaxf(self_hi.y - s_hi.y, 0.f);
  t_hi.z = lpside ? fmaxf(s_hi.z, 0.f) : fmaxf(self_hi.z - s_hi.z, 0.f);
  t_hi.w = lpside ? fmaxf(s_hi.w, 0.f) : fmaxf(self_hi.w - s_hi.w, 0.f);

  float4 o_lo = shfl_xor4(t_lo, 16), o_hi = shfl_xor4(t_hi, 16);

  int c0 = (sl & 15) * 8;
  uint4 hu = *(const uint4*)(const void*)(h_all + (size_t)node * 384 + 256 + c0);
  float4 hi_lo, hi_hi; unpack8(hu, hi_lo, hi_hi);

  const float* wsel = lpside ? wll : wlh;
  float4 w_lo = *(const float4*)(wsel + c0);
  float4 w_hi = *(const float4*)(wsel + c0 + 4);
  float4 wi_lo = *(const float4*)(wli + c0);
  float4 wi_hi = *(const float4*)(wli + c0 + 4);

  float dpart = t_lo.x * w_lo.x + t_lo.y * w_lo.y + t_lo.z * w_lo.z + t_lo.w * w_lo.w
              + t_hi.x * w_hi.x + t_hi.y * w_hi.y + t_hi.z * w_hi.z + t_hi.w * w_hi.w;
  float dipart = hi_lo.x * wi_lo.x + hi_lo.y * wi_lo.y + hi_lo.z * wi_lo.z + hi_lo.w * wi_lo.w
               + hi_hi.x * wi_hi.x + hi_hi.y * wi_hi.y + hi_hi.z * wi_hi.z + hi_hi.w * wi_hi.w;
#pragma unroll
  for (int o = 1; o <= 8; o <<= 1) {
    dpart += __shfl_xor(dpart, o);
    dipart += __shfl_xor(dipart, o);
  }
  float dother = __shfl_xor(dpart, 16);
  float dh = lpside ? dother : dpart;
  float dl = lpside ? dpart : dother;

  float a_h = 1.f / (1.f + __expf(-(dh + pbh[0])));
  float a_l = 1.f / (1.f + __expf(-(dl + pbl[0])));
  float a_i = 1.f / (1.f + __expf(-(dipart + pbi[0])));

  if (lane < 16) {
    f32x4 r_lo, r_hi;
    r_lo[0] = a_h * t_lo.x + a_l * o_lo.x + a_i * hi_lo.x;
    r_lo[1] = a_h * t_lo.y + a_l * o_lo.y + a_i * hi_lo.y;
    r_lo[2] = a_h * t_lo.z + a_l * o_lo.z + a_i * hi_lo.z;
    r_lo[3] = a_h * t_lo.w + a_l * o_lo.w + a_i * hi_lo.w;
    r_hi[0] = a_h * t_hi.x + a_l * o_hi.x + a_i * hi_hi.x;
    r_hi[1] = a_h * t_hi.y + a_l * o_hi.y + a_i * hi_hi.y;
    r_hi[2] = a_h * t_hi.z + a_l * o_hi.z + a_i * hi_hi.z;
    r_hi[3] = a_h * t_hi.w + a_l * o_hi.w + a_i * hi_hi.w;
    f32x4* po = (f32x4*)(out + (size_t)node * 128 + c0);
    __builtin_nontemporal_store(r_lo, po);
    __builtin_nontemporal_store(r_hi, po + 1);
  }
}

// ================= launch ===================================================
extern "C" void kernel_launch(void* const* d_in, const int* in_sizes, int n_in,
                              void* d_out, int out_size, void* d_ws, size_t ws_size,
                              hipStream_t stream) {
  const float* x     = (const float*)d_in[0];
  const int*   ei    = (const int*)d_in[1];
  const float* W_hp  = (const float*)d_in[2];
  const float* b_hp  = (const float*)d_in[3];
  const float* W_lp  = (const float*)d_in[4];
  const float* b_lp  = (const float*)d_in[5];
  const float* W_i   = (const float*)d_in[6];
  const float* b_i   = (const float*)d_in[7];
  const float* wlh   = (const float*)d_in[8];
  const float* pbh   = (const float*)d_in[9];
  const float* wll   = (const float*)d_in[10];
  const float* pbl   = (const float*)d_in[11];
  const float* wli   = (const float*)d_in[12];
  const float* pbi   = (const float*)d_in[13];
  float* out = (float*)d_out;

  int N = in_sizes[0] / 128;
  int E = in_sizes[1] / 2;
  int NB = (N + 255) / 256;

  ushort* xb    = (ushort*)d_ws;                  // N*128
  ushort* h_all = xb + (size_t)N * 128;           // N*384
  ushort* Wb    = h_all + (size_t)N * 384;        // 3*16384
  int2*   edata = (int2*)(Wb + 3 * 16384);        // E
  float*  dinv  = (float*)(edata + E);            // N
  int*    cnt   = (int*)(dinv + N);               // N
  int*    off   = cnt + N;                        // N+1
  int*    cursor= off + N + 1;                    // N
  int*    btot  = cursor + N;                     // 256

  k_prep<<<2048, 256, 0, stream>>>(x, xb, W_hp, W_lp, W_i, Wb, cnt, N);
  k_count<<<(E + 255) / 256, 256, 0, stream>>>(ei + E, cnt, E);
  k_scanA<<<NB, 256, 0, stream>>>(cnt, off, dinv, btot, N);
  k_scanBC<<<NB, 256, 0, stream>>>(off, btot, cursor, N, E, NB);
  k_scatter<<<(E + 255) / 256, 256, 0, stream>>>(ei, dinv, cursor, edata, E);
  k_gemm_mfma<<<dim3(391, 3), 256, 0, stream>>>(xb, Wb, b_hp, b_lp, b_i, h_all, N);
  k_agg_final<<<(N + 3) / 4, 256, 0, stream>>>(
      h_all, dinv, off, edata, wlh, wll, wli, pbh, pbl, pbi, out, N);
}

// Round 7
// 264.899 us; speedup vs baseline: 2.2442x; 1.0511x over previous
//
#include <hip/hip_runtime.h>
#include <cstdint>
#include <cstddef>

#define DEV __device__ __forceinline__

typedef __bf16 bf16x8 __attribute__((ext_vector_type(8)));
typedef float f32x4 __attribute__((ext_vector_type(4)));
typedef unsigned short ushort8v __attribute__((ext_vector_type(8)));

DEV ushort f2b(float f) {
  uint u = __float_as_uint(f);
  return (ushort)((u + 0x7FFFu + ((u >> 16) & 1u)) >> 16);
}

DEV ushort4 cvt4(float4 v) {
  ushort4 o; o.x = f2b(v.x); o.y = f2b(v.y); o.z = f2b(v.z); o.w = f2b(v.w);
  return o;
}

DEV float4 shfl_xor4(float4 v, int m) {
  float4 r;
  r.x = __shfl_xor(v.x, m); r.y = __shfl_xor(v.y, m);
  r.z = __shfl_xor(v.z, m); r.w = __shfl_xor(v.w, m);
  return r;
}

DEV float4 unpack4(uint2 u) {
  float4 r;
  r.x = __uint_as_float(u.x << 16);
  r.y = __uint_as_float(u.x & 0xFFFF0000u);
  r.z = __uint_as_float(u.y << 16);
  r.w = __uint_as_float(u.y & 0xFFFF0000u);
  return r;
}

DEV void fma4(float4& a, float w, uint2 u) {
  float4 v = unpack4(u);
  a.x = fmaf(w, v.x, a.x); a.y = fmaf(w, v.y, a.y);
  a.z = fmaf(w, v.z, a.z); a.w = fmaf(w, v.w, a.w);
}

// ========== degree count (+3 tail blocks convert W to bf16) ==========
__global__ __launch_bounds__(256) void k_count_cvtw(
    const int* __restrict__ col, int* __restrict__ cnt, int E, int nCB,
    const float* __restrict__ W0, const float* __restrict__ W1,
    const float* __restrict__ W2, ushort* __restrict__ Wb) {
  int b = blockIdx.x;
  if (b >= nCB) {
    int mi = b - nCB;
    const float* src = (mi == 0) ? W0 : (mi == 1) ? W1 : W2;
    ushort* dst = Wb + mi * 16384;
    for (int i = threadIdx.x * 4; i < 16384; i += 1024)
      *(ushort4*)(dst + i) = cvt4(*(const float4*)(src + i));
    return;
  }
  int e = b * 256 + threadIdx.x;
  if (e < E) atomicAdd(&cnt[col[e]], 1);
}

// ---------------- scan phase A: per-256-chunk scan + dinv ----------------
__global__ __launch_bounds__(256) void k_scanA(const int* __restrict__ cnt,
                                               int* __restrict__ off,
                                               float* __restrict__ dinv,
                                               int* __restrict__ btot, int N) {
  __shared__ int ws[4];
  int t = threadIdx.x, ln = t & 63, wv = t >> 6;
  int i = blockIdx.x * 256 + t;
  int v = (i < N) ? cnt[i] : 0;
  int inc = v;
#pragma unroll
  for (int o = 1; o < 64; o <<= 1) {
    int u = __shfl_up(inc, o);
    if (ln >= o) inc += u;
  }
  if (ln == 63) ws[wv] = inc;
  __syncthreads();
  if (t == 0) {
    int s = 0;
#pragma unroll
    for (int w = 0; w < 4; ++w) { int tmp = ws[w]; ws[w] = s; s += tmp; }
  }
  __syncthreads();
  int excl = ws[wv] + inc - v;
  if (i < N) {
    off[i] = excl;
    dinv[i] = rsqrtf((float)v + 1.0f);
  }
  if (t == 255) btot[blockIdx.x] = excl + v;
}

// -------- scan phase B+C fused: every block rescans btot, applies prefix ----
__global__ __launch_bounds__(256) void k_scanBC(int* __restrict__ off,
                                                const int* __restrict__ btot,
                                                int* __restrict__ cursor,
                                                int N, int E, int NB) {
  __shared__ int ws[4];
  __shared__ int pre_sh[256];
  int t = threadIdx.x, ln = t & 63, wv = t >> 6;
  int v = (t < NB) ? btot[t] : 0;
  int inc = v;
#pragma unroll
  for (int o = 1; o < 64; o <<= 1) {
    int u = __shfl_up(inc, o);
    if (ln >= o) inc += u;
  }
  if (ln == 63) ws[wv] = inc;
  __syncthreads();
  if (t == 0) {
    int s = 0;
#pragma unroll
    for (int w = 0; w < 4; ++w) { int tmp = ws[w]; ws[w] = s; s += tmp; }
  }
  __syncthreads();
  pre_sh[t] = ws[wv] + inc - v;
  __syncthreads();
  int bpre = pre_sh[blockIdx.x];
  int i = blockIdx.x * 256 + t;
  if (i < N) {
    int o = off[i] + bpre;
    off[i] = o;
    cursor[i] = o;
  }
  if (blockIdx.x == 0 && t == 0) off[N] = E;
}

// ---------------- scatter edges into CSR ----------------
__global__ __launch_bounds__(256) void k_scatter(const int* __restrict__ ei,
                                                 const float* __restrict__ dinv,
                                                 int* __restrict__ cursor,
                                                 int2* __restrict__ edata, int E) {
  int e = blockIdx.x * 256 + threadIdx.x;
  if (e >= E) return;
  int s = ei[e], d = ei[E + e];
  float w = dinv[s] * dinv[d];
  int p = atomicAdd(&cursor[d], 1);
  int2 v; v.x = s; v.y = __float_as_int(w);
  edata[p] = v;
}

// ========== fused GEMM: read x fp32 once, all 3 matrices, W via LDS =========
// 512 threads = 8 waves, 1 row-tile (16 rows) per wave. W_m staged in 32KB LDS
// with XOR swizzle byte ^= (row&7)<<4 so ds_read_b128 of a fragment
// (16 lanes at row stride 256B) is conflict-free.
__global__ __launch_bounds__(512) void k_gemm_fused(
    const float* __restrict__ x, const ushort* __restrict__ Wb,
    const float* __restrict__ b_hp, const float* __restrict__ b_lp,
    const float* __restrict__ b_i,
    ushort* __restrict__ h_all, int N) {
  __shared__ ushort Wl[16384];
  int tid = (int)threadIdx.x, lane = tid & 63, wv = tid >> 6;
  int r = lane & 15, g = lane >> 4;
  int NT = N >> 4;
  int t = blockIdx.x * 8 + wv;
  bool active = t < NT;

  // A-frags: x rows t*16+r, fp32 -> bf16 in-register; persist across all 3 m.
  bf16x8 Af[4];
  if (active) {
    const float* xp = x + ((size_t)t * 16 + r) * 128 + g * 8;
#pragma unroll
    for (int kc = 0; kc < 4; ++kc) {
      float4 v0 = *(const float4*)(xp + kc * 32);
      float4 v1 = *(const float4*)(xp + kc * 32 + 4);
      ushort8v u;
      u[0] = f2b(v0.x); u[1] = f2b(v0.y); u[2] = f2b(v0.z); u[3] = f2b(v0.w);
      u[4] = f2b(v1.x); u[5] = f2b(v1.y); u[6] = f2b(v1.z); u[7] = f2b(v1.w);
      Af[kc] = __builtin_bit_cast(bf16x8, u);
    }
  }

  for (int m = 0; m < 3; ++m) {
    __syncthreads();
    // stage W_m (16384 bf16 = 2048 x 16B), swizzled
    for (int i = tid; i < 2048; i += 512) {
      int byte = i << 4;
      int row = byte >> 8;
      int swz = byte ^ ((row & 7) << 4);
      *(ushort8v*)((char*)Wl + swz) = *(const ushort8v*)(Wb + m * 16384 + (i << 3));
    }
    __syncthreads();
    if (!active) continue;
    const float* bias = (m == 0) ? b_hp : (m == 1) ? b_lp : b_i;
    f32x4 acc[8];
#pragma unroll
    for (int ct = 0; ct < 8; ++ct) {
      float bb = bias[ct * 16 + r];
      f32x4 c; c[0] = bb; c[1] = bb; c[2] = bb; c[3] = bb;
      acc[ct] = c;
    }
#pragma unroll
    for (int kc = 0; kc < 4; ++kc)
#pragma unroll
      for (int ct = 0; ct < 8; ++ct) {
        int row = ct * 16 + r;
        int byte = row * 256 + kc * 64 + g * 16;
        int swz = byte ^ ((row & 7) << 4);
        bf16x8 B = *(const bf16x8*)((const char*)Wl + swz);
        acc[ct] = __builtin_amdgcn_mfma_f32_16x16x32_bf16(Af[kc], B, acc[ct], 0, 0, 0);
      }
    ushort* op = h_all + (size_t)(t * 16 + g * 4) * 384 + m * 128 + r;
#pragma unroll
    for (int ct = 0; ct < 8; ++ct)
#pragma unroll
      for (int j = 0; j < 4; ++j) {
        float v = acc[ct][j];
        if (m == 2) v = fmaxf(v, 0.f);
        op[(size_t)j * 384 + ct * 16] = f2b(v);
      }
  }
}

// ========== fused aggregation + epilogue (round-3 structure, 4-wide) ========
// h_all row: [0:128]=h_hp, [128:256]=h_lp, [256:384]=H_i (bf16).
// Full wave covers one edge's 512B hp|lp row: lane holds 8B (uint2).
__global__ __launch_bounds__(256) void k_agg_final(
    const ushort* __restrict__ h_all, const float* __restrict__ dinv,
    const int* __restrict__ off, const int2* __restrict__ edata,
    const float* __restrict__ wlh, const float* __restrict__ wll,
    const float* __restrict__ wli,
    const float* __restrict__ pbh, const float* __restrict__ pbl,
    const float* __restrict__ pbi,
    float* __restrict__ out, int N) {
  int wv = (int)threadIdx.x >> 6;
  int lane = (int)threadIdx.x & 63;
  int node = blockIdx.x * 4 + wv;
  if (node >= N) return;

  const ushort* hb = h_all + 4 * lane;  // + s*384 per edge
  int p0 = off[node], p1 = off[node + 1];

  float4 a0 = {0,0,0,0}, a1 = {0,0,0,0}, a2 = {0,0,0,0}, a3 = {0,0,0,0};
  int p = p0;
  for (; p + 4 <= p1; p += 4) {
    int2 e0 = edata[p], e1 = edata[p + 1], e2 = edata[p + 2], e3 = edata[p + 3];
    uint2 u0 = *(const uint2*)(const void*)(hb + (size_t)e0.x * 384);
    uint2 u1 = *(const uint2*)(const void*)(hb + (size_t)e1.x * 384);
    uint2 u2 = *(const uint2*)(const void*)(hb + (size_t)e2.x * 384);
    uint2 u3 = *(const uint2*)(const void*)(hb + (size_t)e3.x * 384);
    fma4(a0, __int_as_float(e0.y), u0);
    fma4(a1, __int_as_float(e1.y), u1);
    fma4(a2, __int_as_float(e2.y), u2);
    fma4(a3, __int_as_float(e3.y), u3);
  }
  for (; p < p1; ++p) {
    int2 e = edata[p];
    uint2 u = *(const uint2*)(const void*)(hb + (size_t)e.x * 384);
    fma4(a0, __int_as_float(e.y), u);
  }
  float4 own;
  own.x = (a0.x + a1.x) + (a2.x + a3.x);
  own.y = (a0.y + a1.y) + (a2.y + a3.y);
  own.z = (a0.z + a1.z) + (a2.z + a3.z);
  own.w = (a0.w + a1.w) + (a2.w + a3.w);

  float di = dinv[node], wself = di * di;
  float4 sv = unpack4(*(const uint2*)(const void*)(hb + (size_t)node * 384));
  own.x = fmaf(wself, sv.x, own.x); own.y = fmaf(wself, sv.y, own.y);
  own.z = fmaf(wself, sv.z, own.z); own.w = fmaf(wself, sv.w, own.w);

  // exchange halves: lanes<32 hold hp-side, lanes>=32 hold lp-side (same cols)
  float4 oth = shfl_xor4(own, 32);
  float4 svo = shfl_xor4(sv, 32);
  bool hpside = (lane < 32);
  float4 hpSelf, aggHp, aggLp;
  hpSelf.x = hpside ? sv.x : svo.x; hpSelf.y = hpside ? sv.y : svo.y;
  hpSelf.z = hpside ? sv.z : svo.z; hpSelf.w = hpside ? sv.w : svo.w;
  aggHp.x = hpside ? own.x : oth.x; aggHp.y = hpside ? own.y : oth.y;
  aggHp.z = hpside ? own.z : oth.z; aggHp.w = hpside ? own.w : oth.w;
  aggLp.x = hpside ? oth.x : own.x; aggLp.y = hpside ? oth.y : own.y;
  aggLp.z = hpside ? oth.z : own.z; aggLp.w = hpside ? oth.w : own.w;

  float4 Hh, Hl;
  Hh.x = fmaxf(hpSelf.x - aggHp.x, 0.f); Hh.y = fmaxf(hpSelf.y - aggHp.y, 0.f);
  Hh.z = fmaxf(hpSelf.z - aggHp.z, 0.f); Hh.w = fmaxf(hpSelf.w - aggHp.w, 0.f);
  Hl.x = fmaxf(aggLp.x, 0.f); Hl.y = fmaxf(aggLp.y, 0.f);
  Hl.z = fmaxf(aggLp.z, 0.f); Hl.w = fmaxf(aggLp.w, 0.f);

  int c4 = 4 * (lane & 31);
  float4 hi4 = unpack4(*(const uint2*)(const void*)(h_all + (size_t)node * 384 + 256 + c4));
  float4 wh = *(const float4*)(wlh + c4);
  float4 wl = *(const float4*)(wll + c4);
  float4 wi = *(const float4*)(wli + c4);

  float dh = Hh.x * wh.x + Hh.y * wh.y + Hh.z * wh.z + Hh.w * wh.w;
  float dl = Hl.x * wl.x + Hl.y * wl.y + Hl.z * wl.z + Hl.w * wl.w;
  float dd = hi4.x * wi.x + hi4.y * wi.y + hi4.z * wi.z + hi4.w * wi.w;
#pragma unroll
  for (int o = 32; o > 0; o >>= 1) {
    dh += __shfl_xor(dh, o);
    dl += __shfl_xor(dl, o);
    dd += __shfl_xor(dd, o);
  }
  // each column counted twice (both half-waves) -> x0.5
  float a_h = 1.f / (1.f + __expf(-(0.5f * dh + pbh[0])));
  float a_l = 1.f / (1.f + __expf(-(0.5f * dl + pbl[0])));
  float a_i = 1.f / (1.f + __expf(-(0.5f * dd + pbi[0])));

  if (hpside) {
    float4 o4;
    o4.x = a_h * Hh.x + a_l * Hl.x + a_i * hi4.x;
    o4.y = a_h * Hh.y + a_l * Hl.y + a_i * hi4.y;
    o4.z = a_h * Hh.z + a_l * Hl.z + a_i * hi4.z;
    o4.w = a_h * Hh.w + a_l * Hl.w + a_i * hi4.w;
    *(float4*)(out + (size_t)node * 128 + c4) = o4;
  }
}

// ================= launch ===================================================
extern "C" void kernel_launch(void* const* d_in, const int* in_sizes, int n_in,
                              void* d_out, int out_size, void* d_ws, size_t ws_size,
                              hipStream_t stream) {
  const float* x     = (const float*)d_in[0];
  const int*   ei    = (const int*)d_in[1];
  const float* W_hp  = (const float*)d_in[2];
  const float* b_hp  = (const float*)d_in[3];
  const float* W_lp  = (const float*)d_in[4];
  const float* b_lp  = (const float*)d_in[5];
  const float* W_i   = (const float*)d_in[6];
  const float* b_i   = (const float*)d_in[7];
  const float* wlh   = (const float*)d_in[8];
  const float* pbh   = (const float*)d_in[9];
  const float* wll   = (const float*)d_in[10];
  const float* pbl   = (const float*)d_in[11];
  const float* wli   = (const float*)d_in[12];
  const float* pbi   = (const float*)d_in[13];
  float* out = (float*)d_out;

  int N = in_sizes[0] / 128;
  int E = in_sizes[1] / 2;
  int NB = (N + 255) / 256;
  int nCB = (E + 255) / 256;

  ushort* h_all = (ushort*)d_ws;                  // N*384
  ushort* Wb    = h_all + (size_t)N * 384;        // 3*16384
  int2*   edata = (int2*)(Wb + 3 * 16384);        // E
  float*  dinv  = (float*)(edata + E);            // N
  int*    cnt   = (int*)(dinv + N);               // N
  int*    off   = cnt + N;                        // N+1
  int*    cursor= off + N + 1;                    // N
  int*    btot  = cursor + N;                     // 256

  hipMemsetAsync(cnt, 0, sizeof(int) * N, stream);
  k_count_cvtw<<<nCB + 3, 256, 0, stream>>>(ei + E, cnt, E, nCB, W_hp, W_lp, W_i, Wb);
  k_scanA<<<NB, 256, 0, stream>>>(cnt, off, dinv, btot, N);
  k_scanBC<<<NB, 256, 0, stream>>>(off, btot, cursor, N, E, NB);
  k_scatter<<<(E + 255) / 256, 256, 0, stream>>>(ei, dinv, cursor, edata, E);
  k_gemm_fused<<<(N / 16 + 7) / 8, 512, 0, stream>>>(x, Wb, b_hp, b_lp, b_i, h_all, N);
  k_agg_final<<<(N + 3) / 4, 256, 0, stream>>>(
      h_all, dinv, off, edata, wlh, wll, wli, pbh, pbl, pbi, out, N);
}

// Round 9
// 260.828 us; speedup vs baseline: 2.2793x; 1.0156x over previous
//
#include <hip/hip_runtime.h>
#include <cstdint>
#include <cstddef>

#define DEV __device__ __forceinline__

typedef __bf16 bf16x8 __attribute__((ext_vector_type(8)));
typedef float f32x4 __attribute__((ext_vector_type(4)));
typedef unsigned short ushort8v __attribute__((ext_vector_type(8)));

DEV ushort f2b(float f) {
  uint u = __float_as_uint(f);
  return (ushort)((u + 0x7FFFu + ((u >> 16) & 1u)) >> 16);
}

DEV float4 shfl_xor4(float4 v, int m) {
  float4 r;
  r.x = __shfl_xor(v.x, m); r.y = __shfl_xor(v.y, m);
  r.z = __shfl_xor(v.z, m); r.w = __shfl_xor(v.w, m);
  return r;
}

DEV float4 unpack4(uint2 u) {
  float4 r;
  r.x = __uint_as_float(u.x << 16);
  r.y = __uint_as_float(u.x & 0xFFFF0000u);
  r.z = __uint_as_float(u.y << 16);
  r.w = __uint_as_float(u.y & 0xFFFF0000u);
  return r;
}

DEV void fma4(float4& a, float w, uint2 u) {
  float4 v = unpack4(u);
  a.x = fmaf(w, v.x, a.x); a.y = fmaf(w, v.y, a.y);
  a.z = fmaf(w, v.z, a.z); a.w = fmaf(w, v.w, a.w);
}

// ========== fused GEMM (FIRST kernel): also zeroes cnt; W fp32->LDS ==========
// 512 threads = 8 waves, 1 row-tile (16 rows) per wave. W_m converted fp32->bf16
// during LDS staging, XOR-swizzled (byte ^= (row&7)<<4) for conflict-free
// ds_read_b128 of B-fragments (16 lanes at 256B row stride).
__global__ __launch_bounds__(512) void k_gemm_fused(
    const float* __restrict__ x,
    const float* __restrict__ W0, const float* __restrict__ W1,
    const float* __restrict__ W2,
    const float* __restrict__ b_hp, const float* __restrict__ b_lp,
    const float* __restrict__ b_i,
    ushort* __restrict__ h_all, int* __restrict__ cnt, int N) {
  int tid = (int)threadIdx.x;
  // prologue: zero the degree-count array (replaces hipMemsetAsync launch)
  {
    int gsz = (int)gridDim.x * 512;
    for (int i = (int)blockIdx.x * 512 + tid; i < N; i += gsz) cnt[i] = 0;
  }

  __shared__ ushort Wl[16384];
  int lane = tid & 63, wv = tid >> 6;
  int r = lane & 15, g = lane >> 4;
  int NT = N >> 4;
  int t = blockIdx.x * 8 + wv;
  bool active = t < NT;

  // A-frags: x rows t*16+r, fp32 -> bf16 in-register; persist across all 3 m.
  bf16x8 Af[4];
  if (active) {
    const float* xp = x + ((size_t)t * 16 + r) * 128 + g * 8;
#pragma unroll
    for (int kc = 0; kc < 4; ++kc) {
      float4 v0 = *(const float4*)(xp + kc * 32);
      float4 v1 = *(const float4*)(xp + kc * 32 + 4);
      ushort8v u;
      u[0] = f2b(v0.x); u[1] = f2b(v0.y); u[2] = f2b(v0.z); u[3] = f2b(v0.w);
      u[4] = f2b(v1.x); u[5] = f2b(v1.y); u[6] = f2b(v1.z); u[7] = f2b(v1.w);
      Af[kc] = __builtin_bit_cast(bf16x8, u);
    }
  }

  for (int m = 0; m < 3; ++m) {
    const float* Wsrc = (m == 0) ? W0 : (m == 1) ? W1 : W2;
    __syncthreads();
    // stage W_m: fp32 -> bf16, swizzled, 2048 x 16B
    for (int i = tid; i < 2048; i += 512) {
      int byte = i << 4;
      int row = byte >> 8;
      int swz = byte ^ ((row & 7) << 4);
      const float* s = Wsrc + (i << 3);
      float4 v0 = *(const float4*)s;
      float4 v1 = *(const float4*)(s + 4);
      ushort8v u;
      u[0] = f2b(v0.x); u[1] = f2b(v0.y); u[2] = f2b(v0.z); u[3] = f2b(v0.w);
      u[4] = f2b(v1.x); u[5] = f2b(v1.y); u[6] = f2b(v1.z); u[7] = f2b(v1.w);
      *(ushort8v*)((char*)Wl + swz) = u;
    }
    __syncthreads();
    if (!active) continue;
    const float* bias = (m == 0) ? b_hp : (m == 1) ? b_lp : b_i;
    f32x4 acc[8];
#pragma unroll
    for (int ct = 0; ct < 8; ++ct) {
      float bb = bias[ct * 16 + r];
      f32x4 c; c[0] = bb; c[1] = bb; c[2] = bb; c[3] = bb;
      acc[ct] = c;
    }
#pragma unroll
    for (int kc = 0; kc < 4; ++kc)
#pragma unroll
      for (int ct = 0; ct < 8; ++ct) {
        int row = ct * 16 + r;
        int byte = row * 256 + kc * 64 + g * 16;
        int swz = byte ^ ((row & 7) << 4);
        bf16x8 B = *(const bf16x8*)((const char*)Wl + swz);
        acc[ct] = __builtin_amdgcn_mfma_f32_16x16x32_bf16(Af[kc], B, acc[ct], 0, 0, 0);
      }
    ushort* op = h_all + (size_t)(t * 16 + g * 4) * 384 + m * 128 + r;
#pragma unroll
    for (int ct = 0; ct < 8; ++ct)
#pragma unroll
      for (int j = 0; j < 4; ++j) {
        float v = acc[ct][j];
        if (m == 2) v = fmaxf(v, 0.f);
        op[(size_t)j * 384 + ct * 16] = f2b(v);
      }
  }
}

// ---------------- degree count ----------------
__global__ __launch_bounds__(256) void k_count(const int* __restrict__ col,
                                               int* __restrict__ cnt, int E) {
  int e = blockIdx.x * 256 + threadIdx.x;
  if (e < E) atomicAdd(&cnt[col[e]], 1);
}

// ---------------- scan phase A: per-256-chunk scan + dinv ----------------
__global__ __launch_bounds__(256) void k_scanA(const int* __restrict__ cnt,
                                               int* __restrict__ off,
                                               float* __restrict__ dinv,
                                               int* __restrict__ btot, int N) {
  __shared__ int ws[4];
  int t = threadIdx.x, ln = t & 63, wv = t >> 6;
  int i = blockIdx.x * 256 + t;
  int v = (i < N) ? cnt[i] : 0;
  int inc = v;
#pragma unroll
  for (int o = 1; o < 64; o <<= 1) {
    int u = __shfl_up(inc, o);
    if (ln >= o) inc += u;
  }
  if (ln == 63) ws[wv] = inc;
  __syncthreads();
  if (t == 0) {
    int s = 0;
#pragma unroll
    for (int w = 0; w < 4; ++w) { int tmp = ws[w]; ws[w] = s; s += tmp; }
  }
  __syncthreads();
  int excl = ws[wv] + inc - v;
  if (i < N) {
    off[i] = excl;
    dinv[i] = rsqrtf((float)v + 1.0f);
  }
  if (t == 255) btot[blockIdx.x] = excl + v;
}

// -------- scan phase B+C fused: every block rescans btot, applies prefix ----
__global__ __launch_bounds__(256) void k_scanBC(int* __restrict__ off,
                                                const int* __restrict__ btot,
                                                int* __restrict__ cursor,
                                                int N, int E, int NB) {
  __shared__ int ws[4];
  __shared__ int pre_sh[256];
  int t = threadIdx.x, ln = t & 63, wv = t >> 6;
  int v = (t < NB) ? btot[t] : 0;
  int inc = v;
#pragma unroll
  for (int o = 1; o < 64; o <<= 1) {
    int u = __shfl_up(inc, o);
    if (ln >= o) inc += u;
  }
  if (ln == 63) ws[wv] = inc;
  __syncthreads();
  if (t == 0) {
    int s = 0;
#pragma unroll
    for (int w = 0; w < 4; ++w) { int tmp = ws[w]; ws[w] = s; s += tmp; }
  }
  __syncthreads();
  pre_sh[t] = ws[wv] + inc - v;
  __syncthreads();
  int bpre = pre_sh[blockIdx.x];
  int i = blockIdx.x * 256 + t;
  if (i < N) {
    int o = off[i] + bpre;
    off[i] = o;
    cursor[i] = o;
  }
  if (blockIdx.x == 0 && t == 0) off[N] = E;
}

// ---------------- scatter edges into CSR ----------------
__global__ __launch_bounds__(256) void k_scatter(const int* __restrict__ ei,
                                                 const float* __restrict__ dinv,
                                                 int* __restrict__ cursor,
                                                 int2* __restrict__ edata, int E) {
  int e = blockIdx.x * 256 + threadIdx.x;
  if (e >= E) return;
  int s = ei[e], d = ei[E + e];
  float w = dinv[s] * dinv[d];
  int p = atomicAdd(&cursor[d], 1);
  int2 v; v.x = s; v.y = __float_as_int(w);
  edata[p] = v;
}

// ========== fused aggregation + epilogue (wave/node, 8 gathers in flight) ===
// h_all row: [0:128]=h_hp, [128:256]=h_lp, [256:384]=H_i (bf16).
// Full wave covers one edge's 512B hp|lp row: lane holds 8B (uint2).
__global__ __launch_bounds__(256) void k_agg_final(
    const ushort* __restrict__ h_all, const float* __restrict__ dinv,
    const int* __restrict__ off, const int2* __restrict__ edata,
    const float* __restrict__ wlh, const float* __restrict__ wll,
    const float* __restrict__ wli,
    const float* __restrict__ pbh, const float* __restrict__ pbl,
    const float* __restrict__ pbi,
    float* __restrict__ out, int N) {
  int wv = __builtin_amdgcn_readfirstlane((int)threadIdx.x >> 6);
  int lane = (int)threadIdx.x & 63;
  int node = blockIdx.x * 4 + wv;
  if (node >= N) return;

  const ushort* hb = h_all + 4 * lane;  // + s*384 per edge
  int p0 = off[node], p1 = off[node + 1];

  float4 a0 = {0,0,0,0}, a1 = {0,0,0,0}, a2 = {0,0,0,0}, a3 = {0,0,0,0};
  float4 a4 = {0,0,0,0}, a5 = {0,0,0,0}, a6 = {0,0,0,0}, a7 = {0,0,0,0};
  int p = p0;
  for (; p + 8 <= p1; p += 8) {
    int2 e0 = edata[p],     e1 = edata[p + 1], e2 = edata[p + 2], e3 = edata[p + 3];
    int2 e4 = edata[p + 4], e5 = edata[p + 5], e6 = edata[p + 6], e7 = edata[p + 7];
    uint2 u0 = *(const uint2*)(const void*)(hb + (size_t)e0.x * 384);
    uint2 u1 = *(const uint2*)(const void*)(hb + (size_t)e1.x * 384);
    uint2 u2 = *(const uint2*)(const void*)(hb + (size_t)e2.x * 384);
    uint2 u3 = *(const uint2*)(const void*)(hb + (size_t)e3.x * 384);
    uint2 u4 = *(const uint2*)(const void*)(hb + (size_t)e4.x * 384);
    uint2 u5 = *(const uint2*)(const void*)(hb + (size_t)e5.x * 384);
    uint2 u6 = *(const uint2*)(const void*)(hb + (size_t)e6.x * 384);
    uint2 u7 = *(const uint2*)(const void*)(hb + (size_t)e7.x * 384);
    fma4(a0, __int_as_float(e0.y), u0);
    fma4(a1, __int_as_float(e1.y), u1);
    fma4(a2, __int_as_float(e2.y), u2);
    fma4(a3, __int_as_float(e3.y), u3);
    fma4(a4, __int_as_float(e4.y), u4);
    fma4(a5, __int_as_float(e5.y), u5);
    fma4(a6, __int_as_float(e6.y), u6);
    fma4(a7, __int_as_float(e7.y), u7);
  }
  for (; p < p1; ++p) {
    int2 e = edata[p];
    uint2 u = *(const uint2*)(const void*)(hb + (size_t)e.x * 384);
    fma4(a0, __int_as_float(e.y), u);
  }
  float4 own;
  own.x = ((a0.x + a1.x) + (a2.x + a3.x)) + ((a4.x + a5.x) + (a6.x + a7.x));
  own.y = ((a0.y + a1.y) + (a2.y + a3.y)) + ((a4.y + a5.y) + (a6.y + a7.y));
  own.z = ((a0.z + a1.z) + (a2.z + a3.z)) + ((a4.z + a5.z) + (a6.z + a7.z));
  own.w = ((a0.w + a1.w) + (a2.w + a3.w)) + ((a4.w + a5.w) + (a6.w + a7.w));

  float di = dinv[node], wself = di * di;
  float4 sv = unpack4(*(const uint2*)(const void*)(hb + (size_t)node * 384));
  own.x = fmaf(wself, sv.x, own.x); own.y = fmaf(wself, sv.y, own.y);
  own.z = fmaf(wself, sv.z, own.z); own.w = fmaf(wself, sv.w, own.w);

  // exchange halves: lanes<32 hold hp-side, lanes>=32 hold lp-side (same cols)
  float4 oth = shfl_xor4(own, 32);
  float4 svo = shfl_xor4(sv, 32);
  bool hpside = (lane < 32);
  float4 hpSelf, aggHp, aggLp;
  hpSelf.x = hpside ? sv.x : svo.x; hpSelf.y = hpside ? sv.y : svo.y;
  hpSelf.z = hpside ? sv.z : svo.z; hpSelf.w = hpside ? sv.w : svo.w;
  aggHp.x = hpside ? own.x : oth.x; aggHp.y = hpside ? own.y : oth.y;
  aggHp.z = hpside ? own.z : oth.z; aggHp.w = hpside ? own.w : oth.w;
  aggLp.x = hpside ? oth.x : own.x; aggLp.y = hpside ? oth.y : own.y;
  aggLp.z = hpside ? oth.z : own.z; aggLp.w = hpside ? oth.w : own.w;

  float4 Hh, Hl;
  Hh.x = fmaxf(hpSelf.x - aggHp.x, 0.f); Hh.y = fmaxf(hpSelf.y - aggHp.y, 0.f);
  Hh.z = fmaxf(hpSelf.z - aggHp.z, 0.f); Hh.w = fmaxf(hpSelf.w - aggHp.w, 0.f);
  Hl.x = fmaxf(aggLp.x, 0.f); Hl.y = fmaxf(aggLp.y, 0.f);
  Hl.z = fmaxf(aggLp.z, 0.f); Hl.w = fmaxf(aggLp.w, 0.f);

  int c4 = 4 * (lane & 31);
  float4 hi4 = unpack4(*(const uint2*)(const void*)(h_all + (size_t)node * 384 + 256 + c4));
  float4 wh = *(const float4*)(wlh + c4);
  float4 wl = *(const float4*)(wll + c4);
  float4 wi = *(const float4*)(wli + c4);

  float dh = Hh.x * wh.x + Hh.y * wh.y + Hh.z * wh.z + Hh.w * wh.w;
  float dl = Hl.x * wl.x + Hl.y * wl.y + Hl.z * wl.z + Hl.w * wl.w;
  float dd = hi4.x * wi.x + hi4.y * wi.y + hi4.z * wi.z + hi4.w * wi.w;
#pragma unroll
  for (int o = 32; o > 0; o >>= 1) {
    dh += __shfl_xor(dh, o);
    dl += __shfl_xor(dl, o);
    dd += __shfl_xor(dd, o);
  }
  // each column counted twice (both half-waves) -> x0.5
  float a_h = 1.f / (1.f + __expf(-(0.5f * dh + pbh[0])));
  float a_l = 1.f / (1.f + __expf(-(0.5f * dl + pbl[0])));
  float a_i = 1.f / (1.f + __expf(-(0.5f * dd + pbi[0])));

  if (hpside) {
    float4 o4;
    o4.x = a_h * Hh.x + a_l * Hl.x + a_i * hi4.x;
    o4.y = a_h * Hh.y + a_l * Hl.y + a_i * hi4.y;
    o4.z = a_h * Hh.z + a_l * Hl.z + a_i * hi4.z;
    o4.w = a_h * Hh.w + a_l * Hl.w + a_i * hi4.w;
    *(float4*)(out + (size_t)node * 128 + c4) = o4;
  }
}

// ================= launch ===================================================
extern "C" void kernel_launch(void* const* d_in, const int* in_sizes, int n_in,
                              void* d_out, int out_size, void* d_ws, size_t ws_size,
                              hipStream_t stream) {
  const float* x     = (const float*)d_in[0];
  const int*   ei    = (const int*)d_in[1];
  const float* W_hp  = (const float*)d_in[2];
  const float* b_hp  = (const float*)d_in[3];
  const float* W_lp  = (const float*)d_in[4];
  const float* b_lp  = (const float*)d_in[5];
  const float* W_i   = (const float*)d_in[6];
  const float* b_i   = (const float*)d_in[7];
  const float* wlh   = (const float*)d_in[8];
  const float* pbh   = (const float*)d_in[9];
  const float* wll   = (const float*)d_in[10];
  const float* pbl   = (const float*)d_in[11];
  const float* wli   = (const float*)d_in[12];
  const float* pbi   = (const float*)d_in[13];
  float* out = (float*)d_out;

  int N = in_sizes[0] / 128;
  int E = in_sizes[1] / 2;
  int NB = (N + 255) / 256;

  ushort* h_all = (ushort*)d_ws;                  // N*384
  int2*   edata = (int2*)(h_all + (size_t)N * 384); // E
  float*  dinv  = (float*)(edata + E);            // N
  int*    cnt   = (int*)(dinv + N);               // N
  int*    off   = cnt + N;                        // N+1
  int*    cursor= off + N + 1;                    // N
  int*    btot  = cursor + N;                     // 256

  k_gemm_fused<<<(N / 16 + 7) / 8, 512, 0, stream>>>(
      x, W_hp, W_lp, W_i, b_hp, b_lp, b_i, h_all, cnt, N);
  k_count<<<(E + 255) / 256, 256, 0, stream>>>(ei + E, cnt, E);
  k_scanA<<<NB, 256, 0, stream>>>(cnt, off, dinv, btot, N);
  k_scanBC<<<NB, 256, 0, stream>>>(off, btot, cursor, N, E, NB);
  k_scatter<<<(E + 255) / 256, 256, 0, stream>>>(ei, dinv, cursor, edata, E);
  k_agg_final<<<(N + 3) / 4, 256, 0, stream>>>(
      h_all, dinv, off, edata, wlh, wll, wli, pbh, pbl, pbi, out, N);
}